// Round 3
// baseline (517.724 us; speedup 1.0000x reference)
//
#include <hip/hip_runtime.h>

#define N_ROWS 65536
#define DIM    1024
#define KCL    256

typedef __bf16 bf16_t;
typedef __attribute__((ext_vector_type(8))) __bf16 bf16x8;
typedef __attribute__((ext_vector_type(4))) __bf16 bf16x4;
typedef __attribute__((ext_vector_type(4))) float  floatx4;

// ---------------- P0: clusters -> frag-major bf16 pack, c_sq, zero accumulators ----------------
// Bp layout: Bp[(d>>5)*(KCL*32) + col*32 + (d&31)]  (d = reduction index 0..1023)
// so a wave's MFMA B-fragment (16 cols x 32 k) is one contiguous, coalesced 1KB block.
__global__ __launch_bounds__(256)
void prep_clusters(const float* __restrict__ clusters,
                   bf16_t* __restrict__ bp, float* __restrict__ c_sq,
                   float* __restrict__ numer, float* __restrict__ q_sum,
                   float* __restrict__ denom) {
    const int k = blockIdx.x;     // cluster col 0..255
    const int t = threadIdx.x;    // 0..255, owns d = t*4..t*4+3
    const float4 v = ((const float4*)(clusters + (size_t)k * DIM))[t];
    bf16x4 b;
    b[0] = (bf16_t)v.x; b[1] = (bf16_t)v.y; b[2] = (bf16_t)v.z; b[3] = (bf16_t)v.w;
    *(bf16x4*)(bp + (size_t)(t >> 3) * (KCL * 32) + k * 32 + (t & 7) * 4) = b;
    // zero numer row k (ws is poisoned 0xAA each call)
    float4 z = {0.f, 0.f, 0.f, 0.f};
    ((float4*)(numer + (size_t)k * DIM))[t] = z;
    float s = v.x*v.x + v.y*v.y + v.z*v.z + v.w*v.w;
    #pragma unroll
    for (int m = 1; m < 64; m <<= 1) s += __shfl_xor(s, m);
    __shared__ float ps[4];
    if ((t & 63) == 0) ps[t >> 6] = s;
    __syncthreads();
    if (t == 0) {
        c_sq[k] = ps[0] + ps[1] + ps[2] + ps[3];
        q_sum[k] = 0.f;
        denom[k] = 0.f;
    }
}

// ---------------- P1: GEMM + q epilogue ----------------
// 1024 blocks x 512 threads (8 waves). Tile 64(M) x 256(N), BK=64.
// Wave w owns 32-col strip: acc[4][2] = 32 VGPR.  Baseline skeleton (one-K-step-
// ahead register prefetch of ALL global loads) + two structural wins:
//  - B fragments straight from L2 (frag-major Bp), prefetched into bf_nxt[2][2]
//    during the previous MFMA phase -> L2 latency never on the critical path.
//  - A-only XOR-swizzled double-buffered LDS (16 KB), ONE barrier per K-step.
// (512,4): VGPR<=128 -> 2 blocks/CU = 16 waves/CU.
__global__ __launch_bounds__(512, 4)
void gemm_q(const float* __restrict__ x, const bf16_t* __restrict__ bp,
            const float* __restrict__ c_sq, float* __restrict__ q_out,
            float* __restrict__ q_sum) {
    __shared__ __align__(16) bf16_t As[2][64 * 64];   // 16 KB, chunk ^= (row&7) swizzle

    const int tid  = threadIdx.x;
    const int lane = tid & 63;
    const int w    = tid >> 6;          // 0..7: wave's 32-col strip
    const int l15  = lane & 15;
    const int quad = lane >> 4;         // 0..3
    const int l7   = l15 & 7;
    const int wn   = w * 32;
    const int block_row = blockIdx.x * 64;

    // Staging: thread owns float-chunk c8 (8 floats) of row ar.
    const int ar  = tid >> 3;           // 0..63
    const int c8  = tid & 7;
    const int swc = c8 ^ (ar & 7);
    const float* aptr = x + (size_t)(block_row + ar) * DIM + c8 * 8;

    floatx4 acc[4][2];
    #pragma unroll
    for (int mt = 0; mt < 4; mt++)
        #pragma unroll
        for (int nt = 0; nt < 2; nt++) {
            floatx4 zz = {0.f, 0.f, 0.f, 0.f};
            acc[mt][nt] = zz;
        }

    float xp = 0.f;                     // ||x||^2 partial for row ar

    // ---- prologue: A(0) + B(0) loads, stage A(0) into buf 0 ----
    bf16x8 bf_cur[2][2];
    {
        float4 u = *(const float4*)(aptr);
        float4 v = *(const float4*)(aptr + 4);
        #pragma unroll
        for (int kk = 0; kk < 2; kk++)
            #pragma unroll
            for (int nt = 0; nt < 2; nt++)
                bf_cur[kk][nt] = *(const bf16x8*)(bp + (size_t)kk * (KCL * 32)
                                    + (wn + nt * 16 + l15) * 32 + quad * 8);
        xp += u.x*u.x + u.y*u.y + u.z*u.z + u.w*u.w
            + v.x*v.x + v.y*v.y + v.z*v.z + v.w*v.w;
        bf16x8 ab;
        ab[0]=(bf16_t)u.x; ab[1]=(bf16_t)u.y; ab[2]=(bf16_t)u.z; ab[3]=(bf16_t)u.w;
        ab[4]=(bf16_t)v.x; ab[5]=(bf16_t)v.y; ab[6]=(bf16_t)v.z; ab[7]=(bf16_t)v.w;
        *(bf16x8*)(&As[0][ar * 64 + swc * 8]) = ab;
    }
    __syncthreads();

    for (int kb = 0; kb < 16; ++kb) {
        const int cur = kb & 1;
        // --- issue NEXT K-step's A loads, then B loads (all have a full MFMA
        //     phase + barrier to complete; nothing global on this step's path) ---
        float4 u, v;
        bf16x8 bf_nxt[2][2];
        if (kb < 15) {
            const int k1 = (kb + 1) * 64;
            u = *(const float4*)(aptr + k1);
            v = *(const float4*)(aptr + k1 + 4);
            #pragma unroll
            for (int kk = 0; kk < 2; kk++)
                #pragma unroll
                for (int nt = 0; nt < 2; nt++)
                    bf_nxt[kk][nt] = *(const bf16x8*)(bp
                        + (size_t)((kb + 1) * 2 + kk) * (KCL * 32)
                        + (wn + nt * 16 + l15) * 32 + quad * 8);
        }
        // --- MFMA: 2 kk x 4 mt x 2 nt = 16 per K-step (A from LDS, B from regs) ---
        #pragma unroll
        for (int kk = 0; kk < 2; kk++) {
            #pragma unroll
            for (int mt = 0; mt < 4; mt++) {
                bf16x8 af = *(const bf16x8*)(
                    &As[cur][(mt * 16 + l15) * 64 + (((kk * 4 + quad) ^ l7) * 8)]);
                #pragma unroll
                for (int nt = 0; nt < 2; nt++)
                    acc[mt][nt] = __builtin_amdgcn_mfma_f32_16x16x32_bf16(
                        af, bf_cur[kk][nt], acc[mt][nt], 0, 0, 0);
            }
        }
        // --- xsq accum + convert + stage next A tile into the other buffer ---
        if (kb < 15) {
            xp += u.x*u.x + u.y*u.y + u.z*u.z + u.w*u.w
                + v.x*v.x + v.y*v.y + v.z*v.z + v.w*v.w;
            bf16x8 ab;
            ab[0]=(bf16_t)u.x; ab[1]=(bf16_t)u.y; ab[2]=(bf16_t)u.z; ab[3]=(bf16_t)u.w;
            ab[4]=(bf16_t)v.x; ab[5]=(bf16_t)v.y; ab[6]=(bf16_t)v.z; ab[7]=(bf16_t)v.w;
            *(bf16x8*)(&As[cur ^ 1][ar * 64 + swc * 8]) = ab;
            #pragma unroll
            for (int kk = 0; kk < 2; kk++)
                #pragma unroll
                for (int nt = 0; nt < 2; nt++)
                    bf_cur[kk][nt] = bf_nxt[kk][nt];
        }
        __syncthreads();
    }

    // ---- epilogue: reuse As[0] as float scratch (drained by last barrier) ----
    float* scr  = (float*)&As[0][0];
    float* xsq  = scr;          // [64]
    float* rsum = scr + 64;     // [64]
    if (tid < 64) rsum[tid] = 0.f;
    // reduce xp over the 8 chunk-threads of each row (consecutive lanes)
    xp += __shfl_xor(xp, 1); xp += __shfl_xor(xp, 2); xp += __shfl_xor(xp, 4);
    if ((tid & 7) == 0) xsq[ar] = xp;
    __syncthreads();

    float csq_v[2];
    #pragma unroll
    for (int nt = 0; nt < 2; nt++) csq_v[nt] = c_sq[wn + nt * 16 + l15];

    #pragma unroll
    for (int mt = 0; mt < 4; mt++) {
        floatx4 xs4 = *(floatx4*)(xsq + mt * 16 + quad * 4);
        floatx4 rps = {0.f, 0.f, 0.f, 0.f};
        #pragma unroll
        for (int nt = 0; nt < 2; nt++) {
            #pragma unroll
            for (int r = 0; r < 4; r++) {
                float d  = xs4[r] + csq_v[nt] - 2.0f * acc[mt][nt][r];
                float qv = 1.0f / (1.0f + d);   // ALPHA = 1
                acc[mt][nt][r] = qv;
                rps[r] += qv;
            }
        }
        #pragma unroll
        for (int m = 1; m < 16; m <<= 1) {
            rps[0] += __shfl_xor(rps[0], m);
            rps[1] += __shfl_xor(rps[1], m);
            rps[2] += __shfl_xor(rps[2], m);
            rps[3] += __shfl_xor(rps[3], m);
        }
        if (l15 == 0) {
            #pragma unroll
            for (int r = 0; r < 4; r++)
                atomicAdd(&rsum[mt * 16 + quad * 4 + r], rps[r]);
        }
    }
    __syncthreads();

    float colp[2] = {0.f, 0.f};
    #pragma unroll
    for (int mt = 0; mt < 4; mt++) {
        floatx4 rs4 = *(floatx4*)(rsum + mt * 16 + quad * 4);
        floatx4 inv;
        #pragma unroll
        for (int r = 0; r < 4; r++) inv[r] = 1.0f / rs4[r];
        #pragma unroll
        for (int nt = 0; nt < 2; nt++) {
            #pragma unroll
            for (int r = 0; r < 4; r++) {
                float qn = acc[mt][nt][r] * inv[r];
                q_out[(size_t)(block_row + mt * 16 + quad * 4 + r) * KCL
                      + wn + nt * 16 + l15] = qn;
                colp[nt] += qn;
            }
        }
    }
    // wave owns a distinct 32-col strip: reduce over quad, add straight to global
    #pragma unroll
    for (int nt = 0; nt < 2; nt++) {
        colp[nt] += __shfl_xor(colp[nt], 16);
        colp[nt] += __shfl_xor(colp[nt], 32);
    }
    if (lane < 16) {
        atomicAdd(&q_sum[wn + l15], colp[0]);
        atomicAdd(&q_sum[wn + 16 + l15], colp[1]);
    }
}

// ---------------- P2: sharpen + threshold + scatter ----------------
__global__ __launch_bounds__(256)
void sharpen_scatter(const float* __restrict__ q, const float* __restrict__ q_sum,
                     const float* __restrict__ x,
                     float* __restrict__ numer, float* __restrict__ denom) {
    const int tid  = threadIdx.x;
    const int lane = tid & 63;
    const int row  = blockIdx.x * 4 + (tid >> 6);
    const float4 q4 = ((const float4*)(q + (size_t)row * KCL))[lane];
    const float4 s4 = ((const float4*)q_sum)[lane];
    float tx = q4.x * q4.x / s4.x;
    float ty = q4.y * q4.y / s4.y;
    float tz = q4.z * q4.z / s4.z;
    float tw = q4.w * q4.w / s4.w;
    float tsum = tx + ty + tz + tw;
    #pragma unroll
    for (int m = 1; m < 64; m <<= 1) tsum += __shfl_xor(tsum, m);
    // argmax (first-occurrence tie semantics like jnp.argmax)
    float mv = tx; int mi = lane * 4;
    if (ty > mv) { mv = ty; mi = lane * 4 + 1; }
    if (tz > mv) { mv = tz; mi = lane * 4 + 2; }
    if (tw > mv) { mv = tw; mi = lane * 4 + 3; }
    #pragma unroll
    for (int m = 1; m < 64; m <<= 1) {
        float ov = __shfl_xor(mv, m);
        int   oi = __shfl_xor(mi, m);
        if (ov > mv || (ov == mv && oi < mi)) { mv = ov; mi = oi; }
    }
    // relu(v-0.1)+sign(.)*0.1 == (v > 0.1 ? v : 0)
    float wgt = mv / tsum;
    if (wgt > 0.1f) {
        if (lane == 0) atomicAdd(&denom[mi], wgt);
        const float4* xr = (const float4*)(x + (size_t)row * DIM);
        #pragma unroll
        for (int i = 0; i < 4; i++) {
            float4 xv = xr[lane + i * 64];
            int base = mi * DIM + (lane + i * 64) * 4;
            atomicAdd(&numer[base + 0], wgt * xv.x);
            atomicAdd(&numer[base + 1], wgt * xv.y);
            atomicAdd(&numer[base + 2], wgt * xv.z);
            atomicAdd(&numer[base + 3], wgt * xv.w);
        }
    }
}

// ---------------- P3: new_clusters = numer / (denom + eps) ----------------
__global__ __launch_bounds__(256)
void finalize(const float* __restrict__ numer, const float* __restrict__ denom,
              float* __restrict__ outc) {
    const int i = blockIdx.x * 256 + threadIdx.x;   // float4 index, 0..65535
    float4 nv = ((const float4*)numer)[i];
    float dd = denom[i >> 8] + 2.220446049250313e-16f;  // np.finfo(float).eps
    float4 r;
    r.x = nv.x / dd; r.y = nv.y / dd; r.z = nv.z / dd; r.w = nv.w / dd;
    ((float4*)outc)[i] = r;
}

extern "C" void kernel_launch(void* const* d_in, const int* in_sizes, int n_in,
                              void* d_out, int out_size, void* d_ws, size_t ws_size,
                              hipStream_t stream) {
    const float* x        = (const float*)d_in[0];
    const float* clusters = (const float*)d_in[1];
    float* out      = (float*)d_out;
    float* q_out    = out;                               // [N, K]
    float* out_clus = out + (size_t)N_ROWS * KCL;        // [K, D]

    // workspace layout
    float*  numer = (float*)d_ws;                        // K*D floats (1 MB)
    float*  q_sum = numer + (size_t)KCL * DIM;           // K
    float*  denom = q_sum + KCL;                         // K
    float*  c_sq  = denom + KCL;                         // K
    bf16_t* bp    = (bf16_t*)(c_sq + KCL);               // K*D bf16, frag-major (512 KB)

    prep_clusters<<<KCL, 256, 0, stream>>>(clusters, bp, c_sq, numer, q_sum, denom);
    gemm_q<<<N_ROWS / 64, 512, 0, stream>>>(x, bp, c_sq, q_out, q_sum);
    sharpen_scatter<<<N_ROWS / 4, 256, 0, stream>>>(q_out, q_sum, x, numer, denom);
    finalize<<<256, 256, 0, stream>>>(numer, denom, out_clus);
}

// Round 4
// 425.428 us; speedup vs baseline: 1.2169x; 1.2169x over previous
//
#include <hip/hip_runtime.h>

#define N_ROWS 65536
#define DIM    1024
#define KCL    256

typedef __bf16 bf16_t;
typedef __attribute__((ext_vector_type(8))) __bf16 bf16x8;
typedef __attribute__((ext_vector_type(4))) __bf16 bf16x4;
typedef __attribute__((ext_vector_type(4))) float  floatx4;

// ---------------- P0: clusters -> frag-major bf16 pack, c_sq, zero accumulators ----------------
// Bp layout: Bp[(d>>5)*(KCL*32) + col*32 + (d&31)]  (d = reduction index 0..1023)
// so a wave's MFMA B-fragment (16 cols x 32 k) is one contiguous, coalesced 1KB block.
__global__ __launch_bounds__(256)
void prep_clusters(const float* __restrict__ clusters,
                   bf16_t* __restrict__ bp, float* __restrict__ c_sq,
                   float* __restrict__ numer, float* __restrict__ q_sum,
                   float* __restrict__ denom) {
    const int k = blockIdx.x;     // cluster col 0..255
    const int t = threadIdx.x;    // 0..255, owns d = t*4..t*4+3
    const float4 v = ((const float4*)(clusters + (size_t)k * DIM))[t];
    bf16x4 b;
    b[0] = (bf16_t)v.x; b[1] = (bf16_t)v.y; b[2] = (bf16_t)v.z; b[3] = (bf16_t)v.w;
    *(bf16x4*)(bp + (size_t)(t >> 3) * (KCL * 32) + k * 32 + (t & 7) * 4) = b;
    // zero numer row k (ws is poisoned 0xAA each call)
    float4 z = {0.f, 0.f, 0.f, 0.f};
    ((float4*)(numer + (size_t)k * DIM))[t] = z;
    float s = v.x*v.x + v.y*v.y + v.z*v.z + v.w*v.w;
    #pragma unroll
    for (int m = 1; m < 64; m <<= 1) s += __shfl_xor(s, m);
    __shared__ float ps[4];
    if ((t & 63) == 0) ps[t >> 6] = s;
    __syncthreads();
    if (t == 0) {
        c_sq[k] = ps[0] + ps[1] + ps[2] + ps[3];
        q_sum[k] = 0.f;
        denom[k] = 0.f;
    }
}

// ---------------- P1: GEMM + q epilogue ----------------
// 1024 blocks x 512 threads (8 waves). Tile 64(M) x 256(N), BK=64.
// Wave w owns 32-col strip: acc[4][2] = 32 VGPR (unified-file AGPR).
//  - B fragments straight from L2 (frag-major Bp), prefetched one K-step ahead
//    into bf_nxt -> L2 latency never on the critical path.
//  - A-only XOR-swizzled double-buffered LDS (16 KB), ONE barrier per K-step.
// NO occupancy arg in launch_bounds: round-3 evidence shows (512,4) was honored
// as an 8-waves/EU target -> 64-VGPR cap -> per-K-step spill of the A-prefetch
// pair (WRITE_SIZE 324.7 MB vs 67 MB expected = 15*32B*512K threads of scratch).
// Bare bound: allocator picks ~96-128 VGPR, no spill, ~4-5 waves/EU.
__global__ __launch_bounds__(512)
void gemm_q(const float* __restrict__ x, const bf16_t* __restrict__ bp,
            const float* __restrict__ c_sq, float* __restrict__ q_out,
            float* __restrict__ q_sum) {
    __shared__ __align__(16) bf16_t As[2][64 * 64];   // 16 KB, chunk ^= (row&7) swizzle

    const int tid  = threadIdx.x;
    const int lane = tid & 63;
    const int w    = tid >> 6;          // 0..7: wave's 32-col strip
    const int l15  = lane & 15;
    const int quad = lane >> 4;         // 0..3
    const int l7   = l15 & 7;
    const int wn   = w * 32;
    const int block_row = blockIdx.x * 64;

    // Staging: thread owns float-chunk c8 (8 floats) of row ar.
    const int ar  = tid >> 3;           // 0..63
    const int c8  = tid & 7;
    const int swc = c8 ^ (ar & 7);
    const float* aptr = x + (size_t)(block_row + ar) * DIM + c8 * 8;

    floatx4 acc[4][2];
    #pragma unroll
    for (int mt = 0; mt < 4; mt++)
        #pragma unroll
        for (int nt = 0; nt < 2; nt++) {
            floatx4 zz = {0.f, 0.f, 0.f, 0.f};
            acc[mt][nt] = zz;
        }

    float xp = 0.f;                     // ||x||^2 partial for row ar

    // ---- prologue: A(0) + B(0) loads, stage A(0) into buf 0 ----
    bf16x8 bf_cur[2][2];
    {
        float4 u = *(const float4*)(aptr);
        float4 v = *(const float4*)(aptr + 4);
        #pragma unroll
        for (int kk = 0; kk < 2; kk++)
            #pragma unroll
            for (int nt = 0; nt < 2; nt++)
                bf_cur[kk][nt] = *(const bf16x8*)(bp + (size_t)kk * (KCL * 32)
                                    + (wn + nt * 16 + l15) * 32 + quad * 8);
        xp += u.x*u.x + u.y*u.y + u.z*u.z + u.w*u.w
            + v.x*v.x + v.y*v.y + v.z*v.z + v.w*v.w;
        bf16x8 ab;
        ab[0]=(bf16_t)u.x; ab[1]=(bf16_t)u.y; ab[2]=(bf16_t)u.z; ab[3]=(bf16_t)u.w;
        ab[4]=(bf16_t)v.x; ab[5]=(bf16_t)v.y; ab[6]=(bf16_t)v.z; ab[7]=(bf16_t)v.w;
        *(bf16x8*)(&As[0][ar * 64 + swc * 8]) = ab;
    }
    __syncthreads();

    for (int kb = 0; kb < 16; ++kb) {
        const int cur = kb & 1;
        // --- issue NEXT K-step's A loads, then B loads (all have a full MFMA
        //     phase + barrier to complete; nothing global on this step's path) ---
        float4 u, v;
        bf16x8 bf_nxt[2][2];
        if (kb < 15) {
            const int k1 = (kb + 1) * 64;
            u = *(const float4*)(aptr + k1);
            v = *(const float4*)(aptr + k1 + 4);
            #pragma unroll
            for (int kk = 0; kk < 2; kk++)
                #pragma unroll
                for (int nt = 0; nt < 2; nt++)
                    bf_nxt[kk][nt] = *(const bf16x8*)(bp
                        + (size_t)((kb + 1) * 2 + kk) * (KCL * 32)
                        + (wn + nt * 16 + l15) * 32 + quad * 8);
        }
        // --- MFMA: 2 kk x 4 mt x 2 nt = 16 per K-step (A from LDS, B from regs) ---
        #pragma unroll
        for (int kk = 0; kk < 2; kk++) {
            #pragma unroll
            for (int mt = 0; mt < 4; mt++) {
                bf16x8 af = *(const bf16x8*)(
                    &As[cur][(mt * 16 + l15) * 64 + (((kk * 4 + quad) ^ l7) * 8)]);
                #pragma unroll
                for (int nt = 0; nt < 2; nt++)
                    acc[mt][nt] = __builtin_amdgcn_mfma_f32_16x16x32_bf16(
                        af, bf_cur[kk][nt], acc[mt][nt], 0, 0, 0);
            }
        }
        // --- xsq accum + convert + stage next A tile into the other buffer ---
        if (kb < 15) {
            xp += u.x*u.x + u.y*u.y + u.z*u.z + u.w*u.w
                + v.x*v.x + v.y*v.y + v.z*v.z + v.w*v.w;
            bf16x8 ab;
            ab[0]=(bf16_t)u.x; ab[1]=(bf16_t)u.y; ab[2]=(bf16_t)u.z; ab[3]=(bf16_t)u.w;
            ab[4]=(bf16_t)v.x; ab[5]=(bf16_t)v.y; ab[6]=(bf16_t)v.z; ab[7]=(bf16_t)v.w;
            *(bf16x8*)(&As[cur ^ 1][ar * 64 + swc * 8]) = ab;
            #pragma unroll
            for (int kk = 0; kk < 2; kk++)
                #pragma unroll
                for (int nt = 0; nt < 2; nt++)
                    bf_cur[kk][nt] = bf_nxt[kk][nt];
        }
        __syncthreads();
    }

    // ---- epilogue: reuse As[0] as float scratch (drained by last barrier) ----
    float* scr  = (float*)&As[0][0];
    float* xsq  = scr;          // [64]
    float* rsum = scr + 64;     // [64]
    if (tid < 64) rsum[tid] = 0.f;
    // reduce xp over the 8 chunk-threads of each row (consecutive lanes)
    xp += __shfl_xor(xp, 1); xp += __shfl_xor(xp, 2); xp += __shfl_xor(xp, 4);
    if ((tid & 7) == 0) xsq[ar] = xp;
    __syncthreads();

    float csq_v[2];
    #pragma unroll
    for (int nt = 0; nt < 2; nt++) csq_v[nt] = c_sq[wn + nt * 16 + l15];

    #pragma unroll
    for (int mt = 0; mt < 4; mt++) {
        floatx4 xs4 = *(floatx4*)(xsq + mt * 16 + quad * 4);
        floatx4 rps = {0.f, 0.f, 0.f, 0.f};
        #pragma unroll
        for (int nt = 0; nt < 2; nt++) {
            #pragma unroll
            for (int r = 0; r < 4; r++) {
                float d  = xs4[r] + csq_v[nt] - 2.0f * acc[mt][nt][r];
                float qv = 1.0f / (1.0f + d);   // ALPHA = 1
                acc[mt][nt][r] = qv;
                rps[r] += qv;
            }
        }
        #pragma unroll
        for (int m = 1; m < 16; m <<= 1) {
            rps[0] += __shfl_xor(rps[0], m);
            rps[1] += __shfl_xor(rps[1], m);
            rps[2] += __shfl_xor(rps[2], m);
            rps[3] += __shfl_xor(rps[3], m);
        }
        if (l15 == 0) {
            #pragma unroll
            for (int r = 0; r < 4; r++)
                atomicAdd(&rsum[mt * 16 + quad * 4 + r], rps[r]);
        }
    }
    __syncthreads();

    float colp[2] = {0.f, 0.f};
    #pragma unroll
    for (int mt = 0; mt < 4; mt++) {
        floatx4 rs4 = *(floatx4*)(rsum + mt * 16 + quad * 4);
        floatx4 inv;
        #pragma unroll
        for (int r = 0; r < 4; r++) inv[r] = 1.0f / rs4[r];
        #pragma unroll
        for (int nt = 0; nt < 2; nt++) {
            #pragma unroll
            for (int r = 0; r < 4; r++) {
                float qn = acc[mt][nt][r] * inv[r];
                q_out[(size_t)(block_row + mt * 16 + quad * 4 + r) * KCL
                      + wn + nt * 16 + l15] = qn;
                colp[nt] += qn;
            }
        }
    }
    // wave owns a distinct 32-col strip: reduce over quad, add straight to global
    #pragma unroll
    for (int nt = 0; nt < 2; nt++) {
        colp[nt] += __shfl_xor(colp[nt], 16);
        colp[nt] += __shfl_xor(colp[nt], 32);
    }
    if (lane < 16) {
        atomicAdd(&q_sum[wn + l15], colp[0]);
        atomicAdd(&q_sum[wn + 16 + l15], colp[1]);
    }
}

// ---------------- P2: sharpen + threshold + scatter ----------------
__global__ __launch_bounds__(256)
void sharpen_scatter(const float* __restrict__ q, const float* __restrict__ q_sum,
                     const float* __restrict__ x,
                     float* __restrict__ numer, float* __restrict__ denom) {
    const int tid  = threadIdx.x;
    const int lane = tid & 63;
    const int row  = blockIdx.x * 4 + (tid >> 6);
    const float4 q4 = ((const float4*)(q + (size_t)row * KCL))[lane];
    const float4 s4 = ((const float4*)q_sum)[lane];
    float tx = q4.x * q4.x / s4.x;
    float ty = q4.y * q4.y / s4.y;
    float tz = q4.z * q4.z / s4.z;
    float tw = q4.w * q4.w / s4.w;
    float tsum = tx + ty + tz + tw;
    #pragma unroll
    for (int m = 1; m < 64; m <<= 1) tsum += __shfl_xor(tsum, m);
    // argmax (first-occurrence tie semantics like jnp.argmax)
    float mv = tx; int mi = lane * 4;
    if (ty > mv) { mv = ty; mi = lane * 4 + 1; }
    if (tz > mv) { mv = tz; mi = lane * 4 + 2; }
    if (tw > mv) { mv = tw; mi = lane * 4 + 3; }
    #pragma unroll
    for (int m = 1; m < 64; m <<= 1) {
        float ov = __shfl_xor(mv, m);
        int   oi = __shfl_xor(mi, m);
        if (ov > mv || (ov == mv && oi < mi)) { mv = ov; mi = oi; }
    }
    // relu(v-0.1)+sign(.)*0.1 == (v > 0.1 ? v : 0)
    float wgt = mv / tsum;
    if (wgt > 0.1f) {
        if (lane == 0) atomicAdd(&denom[mi], wgt);
        const float4* xr = (const float4*)(x + (size_t)row * DIM);
        #pragma unroll
        for (int i = 0; i < 4; i++) {
            float4 xv = xr[lane + i * 64];
            int base = mi * DIM + (lane + i * 64) * 4;
            atomicAdd(&numer[base + 0], wgt * xv.x);
            atomicAdd(&numer[base + 1], wgt * xv.y);
            atomicAdd(&numer[base + 2], wgt * xv.z);
            atomicAdd(&numer[base + 3], wgt * xv.w);
        }
    }
}

// ---------------- P3: new_clusters = numer / (denom + eps) ----------------
__global__ __launch_bounds__(256)
void finalize(const float* __restrict__ numer, const float* __restrict__ denom,
              float* __restrict__ outc) {
    const int i = blockIdx.x * 256 + threadIdx.x;   // float4 index, 0..65535
    float4 nv = ((const float4*)numer)[i];
    float dd = denom[i >> 8] + 2.220446049250313e-16f;  // np.finfo(float).eps
    float4 r;
    r.x = nv.x / dd; r.y = nv.y / dd; r.z = nv.z / dd; r.w = nv.w / dd;
    ((float4*)outc)[i] = r;
}

extern "C" void kernel_launch(void* const* d_in, const int* in_sizes, int n_in,
                              void* d_out, int out_size, void* d_ws, size_t ws_size,
                              hipStream_t stream) {
    const float* x        = (const float*)d_in[0];
    const float* clusters = (const float*)d_in[1];
    float* out      = (float*)d_out;
    float* q_out    = out;                               // [N, K]
    float* out_clus = out + (size_t)N_ROWS * KCL;        // [K, D]

    // workspace layout
    float*  numer = (float*)d_ws;                        // K*D floats (1 MB)
    float*  q_sum = numer + (size_t)KCL * DIM;           // K
    float*  denom = q_sum + KCL;                         // K
    float*  c_sq  = denom + KCL;                         // K
    bf16_t* bp    = (bf16_t*)(c_sq + KCL);               // K*D bf16, frag-major (512 KB)

    prep_clusters<<<KCL, 256, 0, stream>>>(clusters, bp, c_sq, numer, q_sum, denom);
    gemm_q<<<N_ROWS / 64, 512, 0, stream>>>(x, bp, c_sq, q_out, q_sum);
    sharpen_scatter<<<N_ROWS / 4, 256, 0, stream>>>(q_out, q_sum, x, numer, denom);
    finalize<<<256, 256, 0, stream>>>(numer, denom, out_clus);
}